// Round 5
// baseline (145.992 us; speedup 1.0000x reference)
//
#include <hip/hip_runtime.h>

// OccupancyGridForestAS: per-point voxel lookup in a forest of 64 dense 64^3 grids,
// addressed via an 8^3 block->tree lookup table.
//
// Inputs (setup_inputs order):
//   d_in[0]: pts            float32 [4194304, 3]   (48 MiB, streamed)
//   d_in[1]: occ_val_grid   float32 [64, 64, 64, 64] (64 MiB, random 4B gathers)
//   d_in[2]: block_lookup   int32   [8, 8, 8]      (2 KiB, L1-resident)
// Output: float32 [4194304] (16 MiB, streamed)
//
// R4 fix: __builtin_nontemporal_load/store requires a native vector type, not
// HIP_vector_type<float,4> — use clang ext_vector_type(4).
//
// R3 -> R4/R5 changes (targeting wave-level latency overlap, not per-thread MLP —
// R1->R2 proved per-thread MLP is not the limiter; R3 counters show the kernel
// is intra-chip latency bound: 41us even when fully L3-warm, VALUBusy 12%):
//  * NO __syncthreads / NO LDS: lookup table read directly from global (2KB,
//    L1-resident broadcast) so waves in a block are never lock-stepped.
//  * 4096 blocks x 128 threads (was 2048 x 256): finer scheduling granularity,
//    smoother tail (blocks retire independently, 2 waves each).
//  * Nontemporal loads for the pts stream and nontemporal stores for out:
//    streaming data stops thrashing L1/L2/L3, keeping the grid hot for gathers.
//  * Keep the L3 grid prefetch (R3 showed ~+2us) and PPT=8.

#define LDIM 8
#define RES  64
#define PPT  8   // points per thread

typedef float vf4 __attribute__((ext_vector_type(4)));

__global__ __launch_bounds__(128) void occ_forest_kernel(
    const float* __restrict__ pts,
    const float* __restrict__ grid,
    const int*   __restrict__ lookup,
    float*       __restrict__ out,
    int n8)       // number of 8-point groups (= total threads)
{
    int j = blockIdx.x * blockDim.x + threadIdx.x;

    // --- L3 prefetch of the grid: 8 coalesced float4 loads per thread. ---
    // Total threads (524288) x 32 floats = 16,777,216 floats = whole 64 MiB grid.
    float pf = 0.0f;
    {
        const vf4* g4 = (const vf4*)grid;
        int stride = n8;
#pragma unroll
        for (int s = 0; s < 8; ++s) {
            vf4 t = g4[j + s * stride];
            pf += t.x + t.y + t.z + t.w;   // kept alive by asm at the end
        }
    }

    // 8 points = 24 floats = 6 float4s (96B/thread stride; L1 absorbs the
    // line-split amplification). Nontemporal: don't pollute caches.
    const vf4* p = (const vf4*)(pts + 24 * (long)j);
    vf4 q0 = __builtin_nontemporal_load(p + 0);
    vf4 q1 = __builtin_nontemporal_load(p + 1);
    vf4 q2 = __builtin_nontemporal_load(p + 2);
    vf4 q3 = __builtin_nontemporal_load(p + 3);
    vf4 q4 = __builtin_nontemporal_load(p + 4);
    vf4 q5 = __builtin_nontemporal_load(p + 5);

    float px[PPT] = {q0.x, q0.w, q1.z, q2.y, q3.x, q3.w, q4.z, q5.y};
    float py[PPT] = {q0.y, q1.x, q1.w, q2.z, q3.y, q4.x, q4.w, q5.z};
    float pz[PPT] = {q0.z, q1.y, q2.x, q2.w, q3.z, q4.y, q5.x, q5.w};

    int  idx[PPT];
    bool valid[PPT];

    // Phase 1: pure ALU — compute all gather indices (0 for invalid lanes so
    // they coalesce into a single broadcast line hit).
#pragma unroll
    for (int k = 0; k < PPT; ++k) {
        float x = px[k], y = py[k], z = pz[k];

        int bx = (int)floorf(x);
        int by = (int)floorf(y);
        int bz = (int)floorf(z);
        bool in_dom = (bx >= 0) & (bx < LDIM) &
                      (by >= 0) & (by < LDIM) &
                      (bz >= 0) & (bz < LDIM);
        int cx = min(max(bx, 0), LDIM - 1);
        int cy = min(max(by, 0), LDIM - 1);
        int cz = min(max(bz, 0), LDIM - 1);

        int bidx = lookup[(cx * LDIM + cy) * LDIM + cz];  // 2KB table, L1-resident
        bool v = in_dom & (bidx >= 0);

        // Reference float op sequence, replicated exactly:
        // block_x = 2*(p - bcs) - 1 ; t = (block_x*0.5 + 0.5)*res ; vox = clip(floor(t),0,res-1)
        float bxf = 2.0f * (x - (float)cx) - 1.0f;
        float byf = 2.0f * (y - (float)cy) - 1.0f;
        float bzf = 2.0f * (z - (float)cz) - 1.0f;
        float tx = (bxf * 0.5f + 0.5f) * (float)RES;
        float ty = (byf * 0.5f + 0.5f) * (float)RES;
        float tz = (bzf * 0.5f + 0.5f) * (float)RES;
        int vx = min(max((int)floorf(tx), 0), RES - 1);
        int vy = min(max((int)floorf(ty), 0), RES - 1);
        int vz = min(max((int)floorf(tz), 0), RES - 1);

        int sb = v ? bidx : 0;
        int ii = ((sb * RES + vx) * RES + vy) * RES + vz;  // < 2^24
        idx[k]   = v ? ii : 0;   // invalid -> grid[0]: same-line broadcast, ~free
        valid[k] = v;
    }

    // Phase 2: 8 independent unconditional gathers — all in flight at once.
    float vals[PPT];
#pragma unroll
    for (int k = 0; k < PPT; ++k) {
        vals[k] = grid[idx[k]];
    }

    // Phase 3: select + coalesced nontemporal store.
#pragma unroll
    for (int k = 0; k < PPT; ++k) {
        vals[k] = valid[k] ? vals[k] : 0.0f;
    }

    vf4 o0 = {vals[0], vals[1], vals[2], vals[3]};
    vf4 o1 = {vals[4], vals[5], vals[6], vals[7]};
    vf4* o = (vf4*)(out + 8 * (long)j);
    __builtin_nontemporal_store(o0, o + 0);
    __builtin_nontemporal_store(o1, o + 1);

    // Keep the prefetch accumulator alive without touching the output.
    asm volatile("" :: "v"(pf));
}

extern "C" void kernel_launch(void* const* d_in, const int* in_sizes, int n_in,
                              void* d_out, int out_size, void* d_ws, size_t ws_size,
                              hipStream_t stream) {
    const float* pts    = (const float*)d_in[0];
    const float* grid   = (const float*)d_in[1];
    const int*   lookup = (const int*)d_in[2];
    float*       out    = (float*)d_out;

    // out_size = 4194304, divisible by 8; 8 points per thread.
    int n8 = out_size / PPT;                    // 524288 threads
    int threads = 128;
    int blocks = (n8 + threads - 1) / threads;  // 4096 blocks, 16/CU x 2 waves
    occ_forest_kernel<<<blocks, threads, 0, stream>>>(
        pts, grid, lookup, out, n8);
}

// Round 6
// 140.052 us; speedup vs baseline: 1.0424x; 1.0424x over previous
//
#include <hip/hip_runtime.h>

// OccupancyGridForestAS: per-point voxel lookup in a forest of 64 dense 64^3 grids,
// addressed via an 8^3 block->tree lookup table.
//
// Inputs (setup_inputs order):
//   d_in[0]: pts            float32 [4194304, 3]   (48 MiB, streamed)
//   d_in[1]: occ_val_grid   float32 [64, 64, 64, 64] (64 MiB, ~0.5M random 4B gathers)
//   d_in[2]: block_lookup   int32   [8, 8, 8]      (2 KiB, L1-resident)
// Output: float32 [4194304] (16 MiB, streamed)
//
// R5 -> R6: DROP the grid prefetch. Post-mortem showed the no-prefetch R2
// structure was <=40.6 us while prefetch variants are 44-48 us. Model: the mix
// runs at a ~2.5-2.9 TB/s per-CU miss-tracking ceiling, so total line-miss
// count is what matters; the prefetch added 524K line-misses (64 MiB) for
// gather lines with only ~1.3x reuse. Revert to 256-thread blocks, cached
// loads (NT loads regressed in R5), NT only on output stores (zero reuse).

#define LDIM 8
#define RES  64
#define PPT  8   // points per thread

typedef float vf4 __attribute__((ext_vector_type(4)));

__global__ __launch_bounds__(256) void occ_forest_kernel(
    const float* __restrict__ pts,
    const float* __restrict__ grid,
    const int*   __restrict__ lookup,
    float*       __restrict__ out,
    int n8)       // number of 8-point groups (= total threads)
{
    int j = blockIdx.x * blockDim.x + threadIdx.x;
    if (j >= n8) return;

    // 8 points = 24 floats = 6 float4s, fully coalesced within the wave.
    const vf4* p = (const vf4*)(pts + 24 * (long)j);
    vf4 q0 = p[0];
    vf4 q1 = p[1];
    vf4 q2 = p[2];
    vf4 q3 = p[3];
    vf4 q4 = p[4];
    vf4 q5 = p[5];

    float px[PPT] = {q0.x, q0.w, q1.z, q2.y, q3.x, q3.w, q4.z, q5.y};
    float py[PPT] = {q0.y, q1.x, q1.w, q2.z, q3.y, q4.x, q4.w, q5.z};
    float pz[PPT] = {q0.z, q1.y, q2.x, q2.w, q3.z, q4.y, q5.x, q5.w};

    int  idx[PPT];
    bool valid[PPT];

    // Phase 1: pure ALU — compute all gather indices (0 for invalid lanes so
    // they coalesce into a single broadcast line hit).
#pragma unroll
    for (int k = 0; k < PPT; ++k) {
        float x = px[k], y = py[k], z = pz[k];

        int bx = (int)floorf(x);
        int by = (int)floorf(y);
        int bz = (int)floorf(z);
        bool in_dom = (bx >= 0) & (bx < LDIM) &
                      (by >= 0) & (by < LDIM) &
                      (bz >= 0) & (bz < LDIM);
        int cx = min(max(bx, 0), LDIM - 1);
        int cy = min(max(by, 0), LDIM - 1);
        int cz = min(max(bz, 0), LDIM - 1);

        int bidx = lookup[(cx * LDIM + cy) * LDIM + cz];  // 2KB table, L1-resident
        bool v = in_dom & (bidx >= 0);

        // Reference float op sequence, replicated exactly:
        // block_x = 2*(p - bcs) - 1 ; t = (block_x*0.5 + 0.5)*res ; vox = clip(floor(t),0,res-1)
        float bxf = 2.0f * (x - (float)cx) - 1.0f;
        float byf = 2.0f * (y - (float)cy) - 1.0f;
        float bzf = 2.0f * (z - (float)cz) - 1.0f;
        float tx = (bxf * 0.5f + 0.5f) * (float)RES;
        float ty = (byf * 0.5f + 0.5f) * (float)RES;
        float tz = (bzf * 0.5f + 0.5f) * (float)RES;
        int vx = min(max((int)floorf(tx), 0), RES - 1);
        int vy = min(max((int)floorf(ty), 0), RES - 1);
        int vz = min(max((int)floorf(tz), 0), RES - 1);

        int sb = v ? bidx : 0;
        int ii = ((sb * RES + vx) * RES + vy) * RES + vz;  // < 2^24
        idx[k]   = v ? ii : 0;   // invalid -> grid[0]: same-line broadcast, ~free
        valid[k] = v;
    }

    // Phase 2: 8 independent unconditional gathers — all in flight at once.
    float vals[PPT];
#pragma unroll
    for (int k = 0; k < PPT; ++k) {
        vals[k] = grid[idx[k]];
    }

    // Phase 3: select + coalesced nontemporal store (out has zero reuse).
#pragma unroll
    for (int k = 0; k < PPT; ++k) {
        vals[k] = valid[k] ? vals[k] : 0.0f;
    }

    vf4 o0 = {vals[0], vals[1], vals[2], vals[3]};
    vf4 o1 = {vals[4], vals[5], vals[6], vals[7]};
    vf4* o = (vf4*)(out + 8 * (long)j);
    __builtin_nontemporal_store(o0, o + 0);
    __builtin_nontemporal_store(o1, o + 1);
}

extern "C" void kernel_launch(void* const* d_in, const int* in_sizes, int n_in,
                              void* d_out, int out_size, void* d_ws, size_t ws_size,
                              hipStream_t stream) {
    const float* pts    = (const float*)d_in[0];
    const float* grid   = (const float*)d_in[1];
    const int*   lookup = (const int*)d_in[2];
    float*       out    = (float*)d_out;

    // out_size = 4194304, divisible by 8; 8 points per thread.
    int n8 = out_size / PPT;                    // 524288 threads
    int threads = 256;
    int blocks = (n8 + threads - 1) / threads;  // 2048 blocks = 8/CU
    occ_forest_kernel<<<blocks, threads, 0, stream>>>(
        pts, grid, lookup, out, n8);
}